// Round 1
// baseline (1281.764 us; speedup 1.0000x reference)
//
#include <hip/hip_runtime.h>

typedef __attribute__((ext_vector_type(8))) short short8;
typedef __attribute__((ext_vector_type(4))) short short4v;
typedef __attribute__((ext_vector_type(4))) float float4v;

#define NB 4
#define NH 16
#define TT 2048
#define DD 1024
#define HD 64
#define LDP 72  // padded LDS row stride in bf16 elems (144 B -> 2-way bank alias = free)

__device__ __forceinline__ short f2bf(float f) {
  union { float f; unsigned u; } x; x.f = f;
  unsigned r = (x.u + 0x7fffu + ((x.u >> 16) & 1u)) >> 16;  // RNE
  return (short)r;
}
__device__ __forceinline__ float bf2f(short s) {
  union { unsigned u; float f; } x;
  x.u = ((unsigned)(unsigned short)s) << 16;
  return x.f;
}

// K -> bf16 [h_all][t][64] ; V -> bf16 transposed [h_all][64][t]
__global__ __launch_bounds__(256) void convert_kv(
    const float* __restrict__ key, const float* __restrict__ value,
    short* __restrict__ Kb, short* __restrict__ Vt) {
  __shared__ __align__(16) short vt[64][LDP];
  int tid = threadIdx.x;
  int h_all = blockIdx.x >> 5;           // 0..63
  int t0 = (blockIdx.x & 31) << 6;       // tile * 64
  int b = h_all >> 4, h = h_all & 15;
  int r = tid >> 2, seg = tid & 3;       // r: row in tile, seg: 16-col group

  const float* kp = key + (size_t)(b * TT + t0 + r) * DD + h * HD + seg * 16;
  const float* vp = value + (size_t)(b * TT + t0 + r) * DD + h * HD + seg * 16;

  // K: straight convert, row-major per head
  short8* kdst = (short8*)(Kb + (size_t)(h_all * TT + t0 + r) * HD + seg * 16);
  for (int half = 0; half < 2; half++) {
    float4v a = *(const float4v*)(kp + half * 8);
    float4v c = *(const float4v*)(kp + half * 8 + 4);
    short8 p;
    p[0] = f2bf(a[0]); p[1] = f2bf(a[1]); p[2] = f2bf(a[2]); p[3] = f2bf(a[3]);
    p[4] = f2bf(c[0]); p[5] = f2bf(c[1]); p[6] = f2bf(c[2]); p[7] = f2bf(c[3]);
    kdst[half] = p;
  }

  // V: transpose via LDS
  for (int half = 0; half < 2; half++) {
    float4v a = *(const float4v*)(vp + half * 8);
    float4v c = *(const float4v*)(vp + half * 8 + 4);
    int cb = seg * 16 + half * 8;
    vt[cb + 0][r] = f2bf(a[0]); vt[cb + 1][r] = f2bf(a[1]);
    vt[cb + 2][r] = f2bf(a[2]); vt[cb + 3][r] = f2bf(a[3]);
    vt[cb + 4][r] = f2bf(c[0]); vt[cb + 5][r] = f2bf(c[1]);
    vt[cb + 6][r] = f2bf(c[2]); vt[cb + 7][r] = f2bf(c[3]);
  }
  __syncthreads();
  short8* vdst = (short8*)(Vt + (size_t)(h_all * HD + r) * TT + t0 + seg * 16);
  vdst[0] = *(const short8*)&vt[r][seg * 16];
  vdst[1] = *(const short8*)&vt[r][seg * 16 + 8];
}

// One block: 128 q-rows of one (b,h). 4 waves x 32 rows (2 row-tiles of 16).
// Phase A: row sums of exp(alpha*S) (no max-subtract: |logit| <= ~18, fp32-safe).
// Phase B: recompute S, w = exp*inv_l, P->LDS (bf16), weights store from LDS
// (coalesced float4), O += P@V via MFMA.
__global__ __launch_bounds__(256, 2) void attn(
    const float* __restrict__ query, const short* __restrict__ Kb,
    const short* __restrict__ Vt, const float* __restrict__ span_scale,
    float* __restrict__ out, float* __restrict__ weights) {
  __shared__ __align__(16) short QP[128][LDP];  // Q staging, then P tile
  __shared__ __align__(16) short Ks[64][LDP];
  __shared__ __align__(16) short Vs[64][LDP];   // [d][k_local]

  int tid = threadIdx.x;
  int h_all = blockIdx.x >> 4;   // 0..63
  int qt = blockIdx.x & 15;
  int b = h_all >> 4, h = h_all & 15;
  int q0 = qt << 7;              // *128

  float ss = span_scale[0];
  float temp = 1.0f + 0.01f * (1.0f - ss);
  float alpha = 0.35355339059327373f / temp;  // 64^-0.25 / temperature

  // ---- stage Q (fp32 -> bf16) into QP ----
  {
    int r2 = tid >> 1, seg = tid & 1;
    const float* qp = query + (size_t)(b * TT + q0 + r2) * DD + h * HD + seg * 32;
    short* dst = &QP[r2][seg * 32];
    for (int i = 0; i < 4; i++) {
      float4v a = *(const float4v*)(qp + 8 * i);
      float4v c = *(const float4v*)(qp + 8 * i + 4);
      short8 p;
      p[0] = f2bf(a[0]); p[1] = f2bf(a[1]); p[2] = f2bf(a[2]); p[3] = f2bf(a[3]);
      p[4] = f2bf(c[0]); p[5] = f2bf(c[1]); p[6] = f2bf(c[2]); p[7] = f2bf(c[3]);
      *(short8*)(dst + 8 * i) = p;
    }
  }
  __syncthreads();

  int w = tid >> 6, lane = tid & 63, quad = lane >> 4, l16 = lane & 15;
  int sr = tid >> 2, sseg = tid & 3;  // staging decomposition for K/V tiles

  // Q A-frags: A[m=l16][k=quad*8+j], 2 row-tiles x 2 k-halves
  short8 qa[2][2];
  for (int rt = 0; rt < 2; rt++)
    for (int hf = 0; hf < 2; hf++)
      qa[rt][hf] = *(const short8*)&QP[w * 32 + rt * 16 + l16][hf * 32 + quad * 8];
  __syncthreads();

  const short* kbase = Kb + (size_t)h_all * TT * HD;
  const short* vbase = Vt + (size_t)h_all * HD * TT;

  // ---- Phase A: row sums ----
  float lsum[2][4];
  for (int rt = 0; rt < 2; rt++)
    for (int r = 0; r < 4; r++) lsum[rt][r] = 0.0f;

  for (int kt = 0; kt < 32; kt++) {
    __syncthreads();
    {
      const short8* g = (const short8*)(kbase + (size_t)(kt * 64 + sr) * HD + sseg * 16);
      *(short8*)&Ks[sr][sseg * 16] = g[0];
      *(short8*)&Ks[sr][sseg * 16 + 8] = g[1];
    }
    __syncthreads();
    for (int n = 0; n < 4; n++) {
      float4v acc0, acc1;
      for (int i = 0; i < 4; i++) { acc0[i] = 0.0f; acc1[i] = 0.0f; }
      for (int hf = 0; hf < 2; hf++) {
        short8 kb = *(const short8*)&Ks[n * 16 + l16][hf * 32 + quad * 8];
        acc0 = __builtin_amdgcn_mfma_f32_16x16x32_bf16(qa[0][hf], kb, acc0, 0, 0, 0);
        acc1 = __builtin_amdgcn_mfma_f32_16x16x32_bf16(qa[1][hf], kb, acc1, 0, 0, 0);
      }
      for (int r = 0; r < 4; r++) {
        lsum[0][r] += __expf(acc0[r] * alpha);
        lsum[1][r] += __expf(acc1[r] * alpha);
      }
    }
  }
  // reduce across the 16 lanes of each quad -> every lane holds its rows' 1/l
  for (int rt = 0; rt < 2; rt++)
    for (int r = 0; r < 4; r++) {
      float v = lsum[rt][r];
      v += __shfl_xor(v, 1); v += __shfl_xor(v, 2);
      v += __shfl_xor(v, 4); v += __shfl_xor(v, 8);
      lsum[rt][r] = 1.0f / v;
    }

  // ---- Phase B: recompute, write weights, accumulate O ----
  float4v oacc[2][4];
  for (int rt = 0; rt < 2; rt++)
    for (int no = 0; no < 4; no++)
      for (int i = 0; i < 4; i++) oacc[rt][no][i] = 0.0f;

  for (int kt = 0; kt < 32; kt++) {
    __syncthreads();
    {
      const short8* gk = (const short8*)(kbase + (size_t)(kt * 64 + sr) * HD + sseg * 16);
      *(short8*)&Ks[sr][sseg * 16] = gk[0];
      *(short8*)&Ks[sr][sseg * 16 + 8] = gk[1];
      const short8* gv = (const short8*)(vbase + (size_t)sr * TT + kt * 64 + sseg * 16);
      *(short8*)&Vs[sr][sseg * 16] = gv[0];
      *(short8*)&Vs[sr][sseg * 16 + 8] = gv[1];
    }
    __syncthreads();

    // S tiles -> w -> P (bf16) in LDS (each wave writes only its own 32 rows)
    for (int n = 0; n < 4; n++) {
      float4v acc0, acc1;
      for (int i = 0; i < 4; i++) { acc0[i] = 0.0f; acc1[i] = 0.0f; }
      for (int hf = 0; hf < 2; hf++) {
        short8 kb = *(const short8*)&Ks[n * 16 + l16][hf * 32 + quad * 8];
        acc0 = __builtin_amdgcn_mfma_f32_16x16x32_bf16(qa[0][hf], kb, acc0, 0, 0, 0);
        acc1 = __builtin_amdgcn_mfma_f32_16x16x32_bf16(qa[1][hf], kb, acc1, 0, 0, 0);
      }
      for (int r = 0; r < 4; r++) {
        float w0 = __expf(acc0[r] * alpha) * lsum[0][r];
        float w1 = __expf(acc1[r] * alpha) * lsum[1][r];
        QP[w * 32 + quad * 4 + r][n * 16 + l16] = f2bf(w0);
        QP[w * 32 + 16 + quad * 4 + r][n * 16 + l16] = f2bf(w1);
      }
    }
    __syncthreads();

    // weights store: read P back in coalesced order, 4x256B segments / instr
    {
      int rr = lane >> 4;          // row within group of 4
      int cc = (lane & 15) * 4;    // 4 cols per lane
      size_t wb = ((size_t)h_all * TT + q0 + w * 32) * TT + kt * 64;
      for (int g = 0; g < 8; g++) {
        int row = g * 4 + rr;
        short4v pv = *(const short4v*)&QP[w * 32 + row][cc];
        float4v f;
        f[0] = bf2f(pv[0]); f[1] = bf2f(pv[1]);
        f[2] = bf2f(pv[2]); f[3] = bf2f(pv[3]);
        *(float4v*)(weights + wb + (size_t)row * TT + cc) = f;
      }
    }

    // O += P @ V
    for (int hf = 0; hf < 2; hf++) {
      short8 pa0 = *(const short8*)&QP[w * 32 + l16][hf * 32 + quad * 8];
      short8 pa1 = *(const short8*)&QP[w * 32 + 16 + l16][hf * 32 + quad * 8];
      for (int no = 0; no < 4; no++) {
        short8 vb = *(const short8*)&Vs[no * 16 + l16][hf * 32 + quad * 8];
        oacc[0][no] = __builtin_amdgcn_mfma_f32_16x16x32_bf16(pa0, vb, oacc[0][no], 0, 0, 0);
        oacc[1][no] = __builtin_amdgcn_mfma_f32_16x16x32_bf16(pa1, vb, oacc[1][no], 0, 0, 0);
      }
    }
  }

  // ---- O store: out[b][t][h*64+d] ----
  for (int rt = 0; rt < 2; rt++)
    for (int no = 0; no < 4; no++)
      for (int r = 0; r < 4; r++) {
        size_t row = (size_t)(b * TT + q0 + w * 32 + rt * 16 + quad * 4 + r);
        out[row * DD + h * HD + no * 16 + l16] = oacc[rt][no][r];
      }
}

extern "C" void kernel_launch(void* const* d_in, const int* in_sizes, int n_in,
                              void* d_out, int out_size, void* d_ws, size_t ws_size,
                              hipStream_t stream) {
  const float* query = (const float*)d_in[0];
  const float* key = (const float*)d_in[1];
  const float* value = (const float*)d_in[2];
  const float* span_scale = (const float*)d_in[5];

  float* out = (float*)d_out;
  float* weights = out + (size_t)NB * TT * DD;  // outputs concatenated flat

  short* Kb = (short*)d_ws;                     // 64 heads * 2048 * 64 bf16 = 16 MB
  short* Vt = Kb + (size_t)64 * TT * HD;        // +16 MB (transposed V)

  convert_kv<<<dim3(2048), dim3(256), 0, stream>>>(key, value, Kb, Vt);
  attn<<<dim3(1024), dim3(256), 0, stream>>>(query, Kb, Vt, span_scale, out, weights);
}